// Round 1
// baseline (729.454 us; speedup 1.0000x reference)
//
#include <hip/hip_runtime.h>
#include <hip/hip_bf16.h>

typedef __bf16 bf16;
typedef __attribute__((ext_vector_type(8))) __bf16 bf16x8;
typedef __attribute__((ext_vector_type(4))) __bf16 bf16x4;
typedef __attribute__((ext_vector_type(4))) float f32x4;

__device__ __forceinline__ bf16 f2bf(float f) { return (bf16)f; }

// async global->LDS, 16B per lane. LDS dest must be uniform-base + lane*16.
__device__ __forceinline__ void async_cp16(const void* g, void* l) {
    __builtin_amdgcn_global_load_lds(
        (const __attribute__((address_space(1))) unsigned int*)g,
        (__attribute__((address_space(3))) unsigned int*)l, 16, 0, 0);
}

// ---------------------------------------------------------------------------
// Positional encoding value for channel c, token t (t = h*64 + w)
// ---------------------------------------------------------------------------
__device__ __forceinline__ float pe_val(int c, int t) {
    int h = t >> 6, w = t & 63;
    int i = c >> 2, j = c & 3;
    float div = expf(-0.14391156831212787f * (float)i);
    float arg = ((j < 2) ? (float)w : (float)h) * div;
    return (j & 1) ? cosf(arg) : sinf(arg);
}

// ---------------------------------------------------------------------------
// Encode: feat (4,256,4096) f32 -> Xb[b,t,c] bf16, P2b bf16 (PE added).
// ---------------------------------------------------------------------------
__global__ __launch_bounds__(1024) void encode_kernel(const float* __restrict__ ref,
                                                      const float* __restrict__ src,
                                                      bf16* __restrict__ Xb,
                                                      bf16* __restrict__ P2b) {
    __shared__ float tile[32][33];
    int n = blockIdx.z >> 1, sel = blockIdx.z & 1;
    const float* f = sel ? src : ref;
    int t = blockIdx.x * 32 + threadIdx.x;
    int c = blockIdx.y * 32 + threadIdx.y;
    float v = f[((size_t)n * 256 + c) * 4096 + t] + pe_val(c, t);
    tile[threadIdx.y][threadIdx.x] = v;
    __syncthreads();
    int tt = blockIdx.x * 32 + threadIdx.y;
    int cc = blockIdx.y * 32 + threadIdx.x;
    float o = tile[threadIdx.x][threadIdx.y];
    int bx = sel ? 4 + n : n;
    int bp = sel ? n : 4 + n;
    Xb [((size_t)bx * 4096 + tt) * 256 + cc] = f2bf(o);
    P2b[((size_t)bp * 4096 + tt) * 256 + cc] = f2bf(o);
}

// ---------------------------------------------------------------------------
// Weight transpose+convert: W[K,N] f32 -> Wt[N,K] bf16, all 24 mats, 1 launch
// Per-layer rows: [0,256)=Wq^T [256,512)=Wk^T [512,768)=Wv^T — contiguous QKV.
// ---------------------------------------------------------------------------
__global__ __launch_bounds__(1024) void wt_conv(const float* __restrict__ Wq, const float* __restrict__ Wk,
                                                const float* __restrict__ Wv, const float* __restrict__ Wo,
                                                const float* __restrict__ W1, const float* __restrict__ W2,
                                                bf16* __restrict__ Wt) {
    __shared__ float t[32][33];
    int z = blockIdx.z, L = z / 6, m = z - L * 6;
    const float* src; int K, N, doff;
    if      (m == 0) { src = Wq + L * 65536;  K = 256; N = 256; doff = 0; }
    else if (m == 1) { src = Wk + L * 65536;  K = 256; N = 256; doff = 65536; }
    else if (m == 2) { src = Wv + L * 65536;  K = 256; N = 256; doff = 131072; }
    else if (m == 3) { src = Wo + L * 65536;  K = 256; N = 256; doff = 196608; }
    else if (m == 4) { src = W1 + L * 131072; K = 256; N = 512; doff = 262144; }
    else             { src = W2 + L * 131072; K = 512; N = 256; doff = 393216; }
    int n0 = blockIdx.x * 32, k0 = blockIdx.y * 32;
    if (n0 >= N || k0 >= K) return;
    t[threadIdx.y][threadIdx.x] = src[(size_t)(k0 + threadIdx.y) * N + n0 + threadIdx.x];
    __syncthreads();
    bf16* dst = Wt + (size_t)L * 524288 + doff;
    dst[(size_t)(n0 + threadIdx.y) * K + k0 + threadIdx.x] = f2bf(t[threadIdx.x][threadIdx.y]);
}

// ---------------------------------------------------------------------------
// Fused QKV GEMM: cols [bn..) of [Q|K|V] = A @ Wt^T + bias, A selected per
// segment: seg0 (Q) <- Aq, seg1/2 (K,V) <- Akv. Self layers: Aq==Akv.
// Q,K get elu+1 epilogue; V plain. K(dim)=256. Output bf16, stride 256.
// ---------------------------------------------------------------------------
__global__ __launch_bounds__(256) void gemm_qkv(const bf16* __restrict__ Aq,
                                                const bf16* __restrict__ Akv,
                                                const bf16* __restrict__ Wt,
                                                const float* __restrict__ bq,
                                                const float* __restrict__ bk,
                                                const float* __restrict__ bv,
                                                bf16* __restrict__ Q,
                                                bf16* __restrict__ Ko,
                                                bf16* __restrict__ V) {
    __shared__ bf16 Als[128 * 64];
    __shared__ bf16 Bls[128 * 64];
    int tid = threadIdx.x;
    int wave = tid >> 6, lane = tid & 63;
    int bm = blockIdx.y * 128, bn = blockIdx.x * 128;
    int wm = (wave >> 1) * 64, wn = (wave & 1) * 64;
    int l15 = lane & 15, g = lane >> 4;
    const int K = 256;

    int seg = bn >> 8, cloc = bn & 255;
    const bf16* A = seg == 0 ? Aq : Akv;
    const float* bias = seg == 0 ? bq : (seg == 1 ? bk : bv);
    bf16* Out = seg == 0 ? Q : (seg == 1 ? Ko : V);
    bool do_elu = seg < 2;

    f32x4 acc[4][4] = {};

    for (int k0 = 0; k0 < K; k0 += 64) {
#pragma unroll
        for (int r = 0; r < 4; ++r) {
            int Lc = r * 256 + tid;
            int row = Lc >> 3, cs = Lc & 7;
            int gc = cs ^ (row & 7);
            async_cp16(A  + (size_t)(bm + row) * K + k0 + gc * 8, &Als[Lc * 8]);
            async_cp16(Wt + (size_t)(bn + row) * K + k0 + gc * 8, &Bls[Lc * 8]);
        }
        __syncthreads();
#pragma unroll
        for (int ks = 0; ks < 2; ++ks) {
            bf16x8 af[4], bfr[4];
#pragma unroll
            for (int i = 0; i < 4; ++i) {
                int row = wm + i * 16 + l15;
                int c = ks * 4 + g;
                af[i] = *(bf16x8*)&Als[row * 64 + ((c ^ (row & 7)) * 8)];
            }
#pragma unroll
            for (int j = 0; j < 4; ++j) {
                int row = wn + j * 16 + l15;
                int c = ks * 4 + g;
                bfr[j] = *(bf16x8*)&Bls[row * 64 + ((c ^ (row & 7)) * 8)];
            }
#pragma unroll
            for (int i = 0; i < 4; ++i)
#pragma unroll
                for (int j = 0; j < 4; ++j)
                    acc[i][j] = __builtin_amdgcn_mfma_f32_16x16x32_bf16(af[i], bfr[j], acc[i][j], 0, 0, 0);
        }
        __syncthreads();
    }

    int r4 = (lane >> 4) * 4;
#pragma unroll
    for (int i = 0; i < 4; ++i) {
#pragma unroll
        for (int j = 0; j < 4; ++j) {
            int cj = cloc + wn + j * 16 + l15;
            float bvv = bias[cj];
#pragma unroll
            for (int r = 0; r < 4; ++r) {
                int row = bm + wm + i * 16 + r4 + r;
                float v = acc[i][j][r] + bvv;
                if (do_elu) v = v > 0.f ? v + 1.f : expf(v);
                Out[(size_t)row * 256 + cj] = f2bf(v);
            }
        }
    }
}

// ---------------------------------------------------------------------------
// MFMA GEMM: C[M,N] bf16 = epi(A[M,K]bf16 @ Wt[N,K]^T + bias). RELU optional.
// ---------------------------------------------------------------------------
template <int RELU>
__global__ __launch_bounds__(256) void gemm_mfma(const bf16* __restrict__ A,
                                                 const bf16* __restrict__ Wt,
                                                 const float* __restrict__ bias,
                                                 bf16* __restrict__ C,
                                                 int N, int K) {
    __shared__ bf16 Als[128 * 64];
    __shared__ bf16 Bls[128 * 64];
    int tid = threadIdx.x;
    int wave = tid >> 6, lane = tid & 63;
    int bm = blockIdx.y * 128, bn = blockIdx.x * 128;
    int wm = (wave >> 1) * 64, wn = (wave & 1) * 64;
    int l15 = lane & 15, g = lane >> 4;

    f32x4 acc[4][4] = {};

    for (int k0 = 0; k0 < K; k0 += 64) {
#pragma unroll
        for (int r = 0; r < 4; ++r) {
            int Lc = r * 256 + tid;
            int row = Lc >> 3, cs = Lc & 7;
            int gc = cs ^ (row & 7);
            async_cp16(A  + (size_t)(bm + row) * K + k0 + gc * 8, &Als[Lc * 8]);
            async_cp16(Wt + (size_t)(bn + row) * K + k0 + gc * 8, &Bls[Lc * 8]);
        }
        __syncthreads();
#pragma unroll
        for (int ks = 0; ks < 2; ++ks) {
            bf16x8 af[4], bfr[4];
#pragma unroll
            for (int i = 0; i < 4; ++i) {
                int row = wm + i * 16 + l15;
                int c = ks * 4 + g;
                af[i] = *(bf16x8*)&Als[row * 64 + ((c ^ (row & 7)) * 8)];
            }
#pragma unroll
            for (int j = 0; j < 4; ++j) {
                int row = wn + j * 16 + l15;
                int c = ks * 4 + g;
                bfr[j] = *(bf16x8*)&Bls[row * 64 + ((c ^ (row & 7)) * 8)];
            }
#pragma unroll
            for (int i = 0; i < 4; ++i)
#pragma unroll
                for (int j = 0; j < 4; ++j)
                    acc[i][j] = __builtin_amdgcn_mfma_f32_16x16x32_bf16(af[i], bfr[j], acc[i][j], 0, 0, 0);
        }
        __syncthreads();
    }

    int r4 = (lane >> 4) * 4;
#pragma unroll
    for (int i = 0; i < 4; ++i) {
#pragma unroll
        for (int j = 0; j < 4; ++j) {
            int col = bn + wn + j * 16 + l15;
            float bvv = bias[col];
#pragma unroll
            for (int r = 0; r < 4; ++r) {
                int row = bm + wm + i * 16 + r4 + r;
                float v = acc[i][j][r] + bvv;
                if (RELU) v = fmaxf(v, 0.f);
                C[(size_t)row * N + col] = f2bf(v);
            }
        }
    }
}

// ---------------------------------------------------------------------------
// KV prep v3: grid (32 sp, 64 nh), 256 thr = 4 waves.
// Block stages 128s x 32ch of K,V (f32, 32 KB LDS, one barrier). Wave w reduces
// s in [w*32, w*32+32): each lane owns 4m x 4d = 16 outputs in regs.
// Cross-wave reduce reuses staging LDS.
// ---------------------------------------------------------------------------
__global__ __launch_bounds__(256) void kv_prep_part(const bf16* __restrict__ Kb,
                                                    const bf16* __restrict__ Vb,
                                                    float* __restrict__ Pkv,
                                                    float* __restrict__ Pks) {
    __shared__ float Ks[128][32];
    __shared__ float Vs[128][32];
    int sp = blockIdx.x;          // 0..31
    int nh = blockIdx.y;          // 0..63
    int n = nh >> 3, h = nh & 7;
    int tid = threadIdx.x;
    int wave = tid >> 6, lane = tid & 63;
    int mg = lane >> 3;           // 0..7  (4 m each)
    int dg = lane & 7;            // 0..7  (4 d each)
    size_t base = ((size_t)n * 4096 + sp * 128) * 256 + h * 32;

#pragma unroll
    for (int p = 0; p < 2; ++p) {
        int r = p * 64 + (tid >> 2);
        int c = (tid & 3) * 8;
        bf16x8 k8 = *(const bf16x8*)(Kb + base + (size_t)r * 256 + c);
        bf16x8 v8 = *(const bf16x8*)(Vb + base + (size_t)r * 256 + c);
#pragma unroll
        for (int u = 0; u < 8; ++u) { Ks[r][c + u] = (float)k8[u]; Vs[r][c + u] = (float)v8[u]; }
    }
    __syncthreads();

    float acc[4][4] = {};
    float ks4[4] = {};
    int s0 = wave * 32;
    for (int s = s0; s < s0 + 32; ++s) {
        float4 kq = *(float4*)&Ks[s][dg * 4];
        float4 vq = *(float4*)&Vs[s][mg * 4];
        ks4[0] += kq.x; ks4[1] += kq.y; ks4[2] += kq.z; ks4[3] += kq.w;
        acc[0][0] += vq.x * kq.x; acc[0][1] += vq.x * kq.y; acc[0][2] += vq.x * kq.z; acc[0][3] += vq.x * kq.w;
        acc[1][0] += vq.y * kq.x; acc[1][1] += vq.y * kq.y; acc[1][2] += vq.y * kq.z; acc[1][3] += vq.y * kq.w;
        acc[2][0] += vq.z * kq.x; acc[2][1] += vq.z * kq.y; acc[2][2] += vq.z * kq.z; acc[2][3] += vq.z * kq.w;
        acc[3][0] += vq.w * kq.x; acc[3][1] += vq.w * kq.y; acc[3][2] += vq.w * kq.z; acc[3][3] += vq.w * kq.w;
    }
    __syncthreads();

    float* R  = &Ks[0][0];
    float* RS = &Vs[0][0];
#pragma unroll
    for (int mi = 0; mi < 4; ++mi)
#pragma unroll
        for (int dj = 0; dj < 4; ++dj)
            R[wave * 1024 + (mg * 4 + mi) * 32 + dg * 4 + dj] = acc[mi][dj];
    if (mg == 0)
#pragma unroll
        for (int dj = 0; dj < 4; ++dj) RS[wave * 32 + dg * 4 + dj] = ks4[dj];
    __syncthreads();

    int e = tid * 4;
    float4 o0 = *(float4*)&R[e];
    float4 o1 = *(float4*)&R[1024 + e];
    float4 o2 = *(float4*)&R[2048 + e];
    float4 o3 = *(float4*)&R[3072 + e];
    float4 o = make_float4(o0.x + o1.x + o2.x + o3.x, o0.y + o1.y + o2.y + o3.y,
                           o0.z + o1.z + o2.z + o3.z, o0.w + o1.w + o2.w + o3.w);
    *(float4*)&Pkv[((size_t)nh * 32 + sp) * 1024 + e] = o;
    if (tid < 32)
        Pks[((size_t)nh * 32 + sp) * 32 + tid] = RS[tid] + RS[32 + tid] + RS[64 + tid] + RS[96 + tid];
}

__global__ __launch_bounds__(256) void kv_reduce(const float* __restrict__ Pkv,
                                                 const float* __restrict__ Pks,
                                                 float* __restrict__ KV,
                                                 float* __restrict__ Ksum) {
    int nh = blockIdx.x;
    int e = threadIdx.x * 4;
    float4 s = make_float4(0.f, 0.f, 0.f, 0.f);
    for (int sp = 0; sp < 32; ++sp) {
        float4 p = *(const float4*)&Pkv[((size_t)nh * 32 + sp) * 1024 + e];
        s.x += p.x; s.y += p.y; s.z += p.z; s.w += p.w;
    }
    *(float4*)&KV[(size_t)nh * 1024 + e] = s;
    if (threadIdx.x < 32) {
        float ss = 0.f;
        for (int sp = 0; sp < 32; ++sp) ss += Pks[((size_t)nh * 32 + sp) * 32 + threadIdx.x];
        Ksum[nh * 32 + threadIdx.x] = ss;
    }
}

// ---------------------------------------------------------------------------
// Attention apply: 32 tokens/block, Q (bf16) tile -> LDS f32, KV row in regs.
// ---------------------------------------------------------------------------
__global__ __launch_bounds__(256) void attn_apply(const bf16* __restrict__ Qb,
                                                  const float* __restrict__ KV,
                                                  const float* __restrict__ Ksum,
                                                  bf16* __restrict__ B) {
    __shared__ float Qs[32][260];
    __shared__ float Zs[32][8];
    int bx = blockIdx.x;
    int n = bx >> 7;
    int tok0 = (bx & 127) << 5;
    int tid = threadIdx.x;

    const bf16* qsrc = Qb + ((size_t)(n * 4096 + tok0)) * 256;
#pragma unroll
    for (int kk = 0; kk < 4; ++kk) {
        int e8 = tid + kk * 256;
        bf16x8 v = *(const bf16x8*)(qsrc + (size_t)e8 * 8);
        int t = e8 >> 5, c8 = e8 & 31;
#pragma unroll
        for (int u = 0; u < 8; ++u) Qs[t][c8 * 8 + u] = (float)v[u];
    }

    int h = tid >> 5, m = tid & 31;
    float kvr[32];
    const float* kvp = KV + (size_t)(n * 8 + h) * 1024 + m * 32;
#pragma unroll
    for (int c = 0; c < 8; ++c) *(float4*)&kvr[c * 4] = *(const float4*)(kvp + c * 4);
    __syncthreads();

    {
        int tz = tid >> 3, hz = tid & 7;
        const float* ksp = Ksum + n * 256 + hz * 32;
        float z = 0.f;
#pragma unroll
        for (int c = 0; c < 8; ++c) {
            float4 q = *(float4*)&Qs[tz][hz * 32 + c * 4];
            float4 k = *(const float4*)(ksp + c * 4);
            z += q.x * k.x + q.y * k.y + q.z * k.z + q.w * k.w;
        }
        Zs[tz][hz] = 1.f / (z + 1e-6f);
    }
    __syncthreads();

    bf16* outp = B + ((size_t)(n * 4096 + tok0)) * 256 + tid;
#pragma unroll 2
    for (int t = 0; t < 32; ++t) {
        float acc = 0.f;
#pragma unroll
        for (int c = 0; c < 8; ++c) {
            float4 q = *(float4*)&Qs[t][h * 32 + c * 4];
            acc += q.x * kvr[c * 4 + 0] + q.y * kvr[c * 4 + 1]
                 + q.z * kvr[c * 4 + 2] + q.w * kvr[c * 4 + 3];
        }
        outp[(size_t)t * 256] = f2bf(acc * Zs[t][h]);
    }
}

// ---------------------------------------------------------------------------
// Residual-add + LayerNorm, bf16 residual stream: Xb = LN(Xb + G) (f32 math).
// One wave per row of 256.
// ---------------------------------------------------------------------------
__global__ __launch_bounds__(256) void ln_res(bf16* __restrict__ Xb,
                                              const bf16* __restrict__ G,
                                              const float* __restrict__ g,
                                              const float* __restrict__ b) {
    int row = blockIdx.x * 4 + (threadIdx.x >> 6);
    int lane = threadIdx.x & 63;
    int c = lane * 4;
    bf16x4 xb = *(const bf16x4*)(Xb + (size_t)row * 256 + c);
    bf16x4 gb = *(const bf16x4*)(G + (size_t)row * 256 + c);
    float4 v;
    v.x = (float)xb[0] + (float)gb[0];
    v.y = (float)xb[1] + (float)gb[1];
    v.z = (float)xb[2] + (float)gb[2];
    v.w = (float)xb[3] + (float)gb[3];
    float s  = v.x + v.y + v.z + v.w;
    float sq = v.x * v.x + v.y * v.y + v.z * v.z + v.w * v.w;
#pragma unroll
    for (int off = 32; off > 0; off >>= 1) {
        s  += __shfl_xor(s,  off);
        sq += __shfl_xor(sq, off);
    }
    float mean = s * (1.f / 256.f);
    float var  = sq * (1.f / 256.f) - mean * mean;
    float rstd = rsqrtf(var + 1e-5f);
    float4 o;
    o.x = (v.x - mean) * rstd * g[c + 0] + b[c + 0];
    o.y = (v.y - mean) * rstd * g[c + 1] + b[c + 1];
    o.z = (v.z - mean) * rstd * g[c + 2] + b[c + 2];
    o.w = (v.w - mean) * rstd * g[c + 3] + b[c + 3];
    bf16x4 ob; ob[0] = f2bf(o.x); ob[1] = f2bf(o.y); ob[2] = f2bf(o.z); ob[3] = f2bf(o.w);
    *(bf16x4*)(Xb + (size_t)row * 256 + c) = ob;
}

// ---------------------------------------------------------------------------
// Store: Xb[b,t,c] bf16 -> out[b,c,t] f32
// ---------------------------------------------------------------------------
__global__ __launch_bounds__(1024) void store_kernel(const bf16* __restrict__ Xb,
                                                     float* __restrict__ out) {
    __shared__ float tile[32][33];
    int b = blockIdx.z;
    int t0 = blockIdx.x * 32, c0 = blockIdx.y * 32;
    tile[threadIdx.y][threadIdx.x] =
        (float)Xb[((size_t)b * 4096 + t0 + threadIdx.y) * 256 + c0 + threadIdx.x];
    __syncthreads();
    out[((size_t)b * 256 + c0 + threadIdx.y) * 4096 + t0 + threadIdx.x] =
        tile[threadIdx.x][threadIdx.y];
}

// ---------------------------------------------------------------------------
// Workspace budget note: previous layout peaked at 92.5 MiB and the tail
// buffers (Kb/Vb) are the prime suspect for an out-of-ws_size write that
// corrupted adjacent input allocations (pre-timing check passed, all
// post-timing launches consistently wrong => persistent input corruption).
// Fix: back Kb+Vb (2*SZ bf16 = 33,554,432 B) with d_out (8*256*4096*4 B =
// 33,554,432 B, exact fit). Lifetimes: Kb/Vb/Bb/Hb are all dead before
// store_kernel writes d_out; both are fully rewritten each call before any
// read. Peak ws usage drops to 60.5 MiB.
// ---------------------------------------------------------------------------
extern "C" void kernel_launch(void* const* d_in, const int* in_sizes, int n_in,
                              void* d_out, int out_size, void* d_ws, size_t ws_size,
                              hipStream_t stream) {
    const float* ref  = (const float*)d_in[0];
    const float* srcf = (const float*)d_in[1];
    const float* Wq = (const float*)d_in[2];
    const float* bq = (const float*)d_in[3];
    const float* Wk = (const float*)d_in[4];
    const float* bk = (const float*)d_in[5];
    const float* Wv = (const float*)d_in[6];
    const float* bv = (const float*)d_in[7];
    const float* Wo = (const float*)d_in[8];
    const float* bo = (const float*)d_in[9];
    const float* W1 = (const float*)d_in[10];
    const float* b1 = (const float*)d_in[11];
    const float* W2 = (const float*)d_in[12];
    const float* b2 = (const float*)d_in[13];
    const float* g1 = (const float*)d_in[14];
    const float* be1 = (const float*)d_in[15];
    const float* g2 = (const float*)d_in[16];
    const float* be2 = (const float*)d_in[17];

    const size_t SZ = (size_t)8 * 4096 * 256;
    float* ws  = (float*)d_ws;
    float* KVb = ws;                          // 65536 f32
    float* Ksb = KVb + 65536;                 // 2048 f32
    float* Pkv = Ksb + 2048;                  // 2,097,152 f32 (64 nh x 32 sp x 1024)
    float* Pks = Pkv + 2097152;               // 65536 f32
    bf16*  Wt  = (bf16*)(Pks + 65536);        // 2,097,152 bf16
    bf16*  Xb  = Wt + 2097152;                // SZ bf16 (residual stream)
    bf16*  P2b = Xb + SZ;                     // SZ bf16 (original features, batch-swapped)
    bf16*  Qb  = P2b + SZ;                    // SZ bf16; also O-GEMM / FFN2 temp output
    // K/V live in d_out (exact 2*SZ bf16 fit); dead before store_kernel runs.
    bf16*  Kb  = (bf16*)d_out;
    bf16*  Vb  = Kb + SZ;
    bf16*  Bb  = Kb;                          // alias: K dead after kv_prep
    bf16*  Hb  = Kb;                          // alias: FFN hidden spans Kb+Vb

    wt_conv<<<dim3(16, 16, 24), dim3(32, 32), 0, stream>>>(Wq, Wk, Wv, Wo, W1, W2, Wt);
    encode_kernel<<<dim3(128, 8, 8), dim3(32, 32), 0, stream>>>(ref, srcf, Xb, P2b);

    for (int L = 0; L < 4; ++L) {
        const bf16* WtL = Wt + (size_t)L * 524288;
        const bf16* Akv = (L & 1) ? P2b : Xb;
        gemm_qkv<<<dim3(6, 256), 256, 0, stream>>>(Xb, Akv, WtL,
                                                   bq + L * 256, bk + L * 256, bv + L * 256,
                                                   Qb, Kb, Vb);
        kv_prep_part<<<dim3(32, 64), 256, 0, stream>>>(Kb, Vb, Pkv, Pks);
        kv_reduce<<<64, 256, 0, stream>>>(Pkv, Pks, KVb, Ksb);
        attn_apply<<<1024, 256, 0, stream>>>(Qb, KVb, Ksb, Bb);
        gemm_mfma<0><<<dim3(2, 256), 256, 0, stream>>>(Bb, WtL + 196608, bo + L * 256, Qb, 256, 256);
        ln_res<<<8192, 256, 0, stream>>>(Xb, Qb, g1 + L * 256, be1 + L * 256);
        gemm_mfma<1><<<dim3(4, 256), 256, 0, stream>>>(Xb, WtL + 262144, b1 + L * 512, Hb, 512, 256);
        gemm_mfma<0><<<dim3(2, 256), 256, 0, stream>>>(Hb, WtL + 393216, b2 + L * 256, Qb, 256, 512);
        ln_res<<<8192, 256, 0, stream>>>(Xb, Qb, g2 + L * 256, be2 + L * 256);
    }

    store_kernel<<<dim3(128, 8, 8), dim3(32, 32), 0, stream>>>(Xb, (float*)d_out);
}

// Round 2
// 691.001 us; speedup vs baseline: 1.0556x; 1.0556x over previous
//
#include <hip/hip_runtime.h>
#include <hip/hip_bf16.h>

typedef __bf16 bf16;
typedef __attribute__((ext_vector_type(8))) __bf16 bf16x8;
typedef __attribute__((ext_vector_type(4))) __bf16 bf16x4;
typedef __attribute__((ext_vector_type(4))) float f32x4;

__device__ __forceinline__ bf16 f2bf(float f) { return (bf16)f; }

// async global->LDS, 16B per lane. LDS dest must be uniform-base + lane*16.
__device__ __forceinline__ void async_cp16(const void* g, void* l) {
    __builtin_amdgcn_global_load_lds(
        (const __attribute__((address_space(1))) unsigned int*)g,
        (__attribute__((address_space(3))) unsigned int*)l, 16, 0, 0);
}

// ---------------------------------------------------------------------------
// Positional encoding value for channel c, token t (t = h*64 + w)
// ---------------------------------------------------------------------------
__device__ __forceinline__ float pe_val(int c, int t) {
    int h = t >> 6, w = t & 63;
    int i = c >> 2, j = c & 3;
    float div = expf(-0.14391156831212787f * (float)i);
    float arg = ((j < 2) ? (float)w : (float)h) * div;
    return (j & 1) ? cosf(arg) : sinf(arg);
}

// ---------------------------------------------------------------------------
// Encode: feat (4,256,4096) f32 -> Xb[b,t,c] bf16, P2b bf16 (PE added).
// ---------------------------------------------------------------------------
__global__ __launch_bounds__(1024) void encode_kernel(const float* __restrict__ ref,
                                                      const float* __restrict__ src,
                                                      bf16* __restrict__ Xb,
                                                      bf16* __restrict__ P2b) {
    __shared__ float tile[32][33];
    int n = blockIdx.z >> 1, sel = blockIdx.z & 1;
    const float* f = sel ? src : ref;
    int t = blockIdx.x * 32 + threadIdx.x;
    int c = blockIdx.y * 32 + threadIdx.y;
    float v = f[((size_t)n * 256 + c) * 4096 + t] + pe_val(c, t);
    tile[threadIdx.y][threadIdx.x] = v;
    __syncthreads();
    int tt = blockIdx.x * 32 + threadIdx.y;
    int cc = blockIdx.y * 32 + threadIdx.x;
    float o = tile[threadIdx.x][threadIdx.y];
    int bx = sel ? 4 + n : n;
    int bp = sel ? n : 4 + n;
    Xb [((size_t)bx * 4096 + tt) * 256 + cc] = f2bf(o);
    P2b[((size_t)bp * 4096 + tt) * 256 + cc] = f2bf(o);
}

// ---------------------------------------------------------------------------
// Weight transpose+convert: W[K,N] f32 -> Wt[N,K] bf16, all 24 mats, 1 launch
// Per-layer rows: [0,256)=Wq^T [256,512)=Wk^T [512,768)=Wv^T — contiguous QKV.
// ---------------------------------------------------------------------------
__global__ __launch_bounds__(1024) void wt_conv(const float* __restrict__ Wq, const float* __restrict__ Wk,
                                                const float* __restrict__ Wv, const float* __restrict__ Wo,
                                                const float* __restrict__ W1, const float* __restrict__ W2,
                                                bf16* __restrict__ Wt) {
    __shared__ float t[32][33];
    int z = blockIdx.z, L = z / 6, m = z - L * 6;
    const float* src; int K, N, doff;
    if      (m == 0) { src = Wq + L * 65536;  K = 256; N = 256; doff = 0; }
    else if (m == 1) { src = Wk + L * 65536;  K = 256; N = 256; doff = 65536; }
    else if (m == 2) { src = Wv + L * 65536;  K = 256; N = 256; doff = 131072; }
    else if (m == 3) { src = Wo + L * 65536;  K = 256; N = 256; doff = 196608; }
    else if (m == 4) { src = W1 + L * 131072; K = 256; N = 512; doff = 262144; }
    else             { src = W2 + L * 131072; K = 512; N = 256; doff = 393216; }
    int n0 = blockIdx.x * 32, k0 = blockIdx.y * 32;
    if (n0 >= N || k0 >= K) return;
    t[threadIdx.y][threadIdx.x] = src[(size_t)(k0 + threadIdx.y) * N + n0 + threadIdx.x];
    __syncthreads();
    bf16* dst = Wt + (size_t)L * 524288 + doff;
    dst[(size_t)(n0 + threadIdx.y) * K + k0 + threadIdx.x] = f2bf(t[threadIdx.x][threadIdx.y]);
}

// ---------------------------------------------------------------------------
// Fused QKV GEMM: cols [bn..) of [Q|K|V] = A @ Wt^T + bias, A selected per
// segment: seg0 (Q) <- Aq, seg1/2 (K,V) <- Akv. Self layers: Aq==Akv.
// Q,K get elu+1 epilogue; V plain. K(dim)=256. Output bf16, stride 256.
// ---------------------------------------------------------------------------
__global__ __launch_bounds__(256) void gemm_qkv(const bf16* __restrict__ Aq,
                                                const bf16* __restrict__ Akv,
                                                const bf16* __restrict__ Wt,
                                                const float* __restrict__ bq,
                                                const float* __restrict__ bk,
                                                const float* __restrict__ bv,
                                                bf16* __restrict__ Q,
                                                bf16* __restrict__ Ko,
                                                bf16* __restrict__ V) {
    __shared__ bf16 Als[128 * 64];
    __shared__ bf16 Bls[128 * 64];
    int tid = threadIdx.x;
    int wave = tid >> 6, lane = tid & 63;
    int bm = blockIdx.y * 128, bn = blockIdx.x * 128;
    int wm = (wave >> 1) * 64, wn = (wave & 1) * 64;
    int l15 = lane & 15, g = lane >> 4;
    const int K = 256;

    int seg = bn >> 8, cloc = bn & 255;
    const bf16* A = seg == 0 ? Aq : Akv;
    const float* bias = seg == 0 ? bq : (seg == 1 ? bk : bv);
    bf16* Out = seg == 0 ? Q : (seg == 1 ? Ko : V);
    bool do_elu = seg < 2;

    f32x4 acc[4][4] = {};

    for (int k0 = 0; k0 < K; k0 += 64) {
#pragma unroll
        for (int r = 0; r < 4; ++r) {
            int Lc = r * 256 + tid;
            int row = Lc >> 3, cs = Lc & 7;
            int gc = cs ^ (row & 7);
            async_cp16(A  + (size_t)(bm + row) * K + k0 + gc * 8, &Als[Lc * 8]);
            async_cp16(Wt + (size_t)(bn + row) * K + k0 + gc * 8, &Bls[Lc * 8]);
        }
        __syncthreads();
#pragma unroll
        for (int ks = 0; ks < 2; ++ks) {
            bf16x8 af[4], bfr[4];
#pragma unroll
            for (int i = 0; i < 4; ++i) {
                int row = wm + i * 16 + l15;
                int c = ks * 4 + g;
                af[i] = *(bf16x8*)&Als[row * 64 + ((c ^ (row & 7)) * 8)];
            }
#pragma unroll
            for (int j = 0; j < 4; ++j) {
                int row = wn + j * 16 + l15;
                int c = ks * 4 + g;
                bfr[j] = *(bf16x8*)&Bls[row * 64 + ((c ^ (row & 7)) * 8)];
            }
#pragma unroll
            for (int i = 0; i < 4; ++i)
#pragma unroll
                for (int j = 0; j < 4; ++j)
                    acc[i][j] = __builtin_amdgcn_mfma_f32_16x16x32_bf16(af[i], bfr[j], acc[i][j], 0, 0, 0);
        }
        __syncthreads();
    }

    int r4 = (lane >> 4) * 4;
#pragma unroll
    for (int i = 0; i < 4; ++i) {
#pragma unroll
        for (int j = 0; j < 4; ++j) {
            int cj = cloc + wn + j * 16 + l15;
            float bvv = bias[cj];
#pragma unroll
            for (int r = 0; r < 4; ++r) {
                int row = bm + wm + i * 16 + r4 + r;
                float v = acc[i][j][r] + bvv;
                if (do_elu) v = v > 0.f ? v + 1.f : expf(v);
                Out[(size_t)row * 256 + cj] = f2bf(v);
            }
        }
    }
}

// ---------------------------------------------------------------------------
// MFMA GEMM: C[M,N] bf16 = epi(A[M,K]bf16 @ Wt[N,K]^T + bias). RELU optional.
// (now used only for FFN1, N=512)
// ---------------------------------------------------------------------------
template <int RELU>
__global__ __launch_bounds__(256) void gemm_mfma(const bf16* __restrict__ A,
                                                 const bf16* __restrict__ Wt,
                                                 const float* __restrict__ bias,
                                                 bf16* __restrict__ C,
                                                 int N, int K) {
    __shared__ bf16 Als[128 * 64];
    __shared__ bf16 Bls[128 * 64];
    int tid = threadIdx.x;
    int wave = tid >> 6, lane = tid & 63;
    int bm = blockIdx.y * 128, bn = blockIdx.x * 128;
    int wm = (wave >> 1) * 64, wn = (wave & 1) * 64;
    int l15 = lane & 15, g = lane >> 4;

    f32x4 acc[4][4] = {};

    for (int k0 = 0; k0 < K; k0 += 64) {
#pragma unroll
        for (int r = 0; r < 4; ++r) {
            int Lc = r * 256 + tid;
            int row = Lc >> 3, cs = Lc & 7;
            int gc = cs ^ (row & 7);
            async_cp16(A  + (size_t)(bm + row) * K + k0 + gc * 8, &Als[Lc * 8]);
            async_cp16(Wt + (size_t)(bn + row) * K + k0 + gc * 8, &Bls[Lc * 8]);
        }
        __syncthreads();
#pragma unroll
        for (int ks = 0; ks < 2; ++ks) {
            bf16x8 af[4], bfr[4];
#pragma unroll
            for (int i = 0; i < 4; ++i) {
                int row = wm + i * 16 + l15;
                int c = ks * 4 + g;
                af[i] = *(bf16x8*)&Als[row * 64 + ((c ^ (row & 7)) * 8)];
            }
#pragma unroll
            for (int j = 0; j < 4; ++j) {
                int row = wn + j * 16 + l15;
                int c = ks * 4 + g;
                bfr[j] = *(bf16x8*)&Bls[row * 64 + ((c ^ (row & 7)) * 8)];
            }
#pragma unroll
            for (int i = 0; i < 4; ++i)
#pragma unroll
                for (int j = 0; j < 4; ++j)
                    acc[i][j] = __builtin_amdgcn_mfma_f32_16x16x32_bf16(af[i], bfr[j], acc[i][j], 0, 0, 0);
        }
        __syncthreads();
    }

    int r4 = (lane >> 4) * 4;
#pragma unroll
    for (int i = 0; i < 4; ++i) {
#pragma unroll
        for (int j = 0; j < 4; ++j) {
            int col = bn + wn + j * 16 + l15;
            float bvv = bias[col];
#pragma unroll
            for (int r = 0; r < 4; ++r) {
                int row = bm + wm + i * 16 + r4 + r;
                float v = acc[i][j][r] + bvv;
                if (RELU) v = fmaxf(v, 0.f);
                C[(size_t)row * N + col] = f2bf(v);
            }
        }
    }
}

// ---------------------------------------------------------------------------
// Fused GEMM (N=256) + residual + LayerNorm epilogue writing Xb in place:
//   Xb = LN(Xb + A @ Wt^T + bias) * g + b
// Block: 512 threads = 8 waves (2 row x 4 col of 64x64), tile 128x256.
// C tile staged in LDS [128][260] bf16 (pad 260: row stride 520B = 2-bank
// shift/row -> quarter-wave rows {0,4,8,12} hit disjoint bank octets).
// Numerics identical to gemm_mfma<0> + ln_res (bf16 C, f32 LN math).
// ---------------------------------------------------------------------------
__global__ __launch_bounds__(512) void gemm_ln(const bf16* __restrict__ A,
                                               const bf16* __restrict__ Wt,
                                               const float* __restrict__ bias,
                                               bf16* __restrict__ Xb,
                                               const float* __restrict__ g,
                                               const float* __restrict__ b,
                                               int K) {
    __shared__ __align__(16) char smem[128 * 260 * 2];  // 66560 B
    bf16* Als = (bf16*)smem;            // [128][64]  16 KB (during K loop)
    bf16* Bls = (bf16*)(smem + 16384);  // [256][64]  32 KB (during K loop)
    bf16* Cls = (bf16*)smem;            // [128][260] after K loop

    int tid = threadIdx.x;
    int wave = tid >> 6, lane = tid & 63;
    int bm = blockIdx.x * 128;
    int wm = (wave >> 2) * 64, wn = (wave & 3) * 64;
    int l15 = lane & 15, gg = lane >> 4;

    f32x4 acc[4][4] = {};

    for (int k0 = 0; k0 < K; k0 += 64) {
#pragma unroll
        for (int r = 0; r < 2; ++r) {   // A tile: 128x64
            int Lc = r * 512 + tid;
            int row = Lc >> 3, cs = Lc & 7;
            int gc = cs ^ (row & 7);
            async_cp16(A + (size_t)(bm + row) * K + k0 + gc * 8, &Als[Lc * 8]);
        }
#pragma unroll
        for (int r = 0; r < 4; ++r) {   // B tile: 256x64
            int Lc = r * 512 + tid;
            int row = Lc >> 3, cs = Lc & 7;
            int gc = cs ^ (row & 7);
            async_cp16(Wt + (size_t)row * K + k0 + gc * 8, &Bls[Lc * 8]);
        }
        __syncthreads();
#pragma unroll
        for (int ks = 0; ks < 2; ++ks) {
            bf16x8 af[4], bfr[4];
#pragma unroll
            for (int i = 0; i < 4; ++i) {
                int row = wm + i * 16 + l15;
                int c = ks * 4 + gg;
                af[i] = *(bf16x8*)&Als[row * 64 + ((c ^ (row & 7)) * 8)];
            }
#pragma unroll
            for (int j = 0; j < 4; ++j) {
                int row = wn + j * 16 + l15;
                int c = ks * 4 + gg;
                bfr[j] = *(bf16x8*)&Bls[row * 64 + ((c ^ (row & 7)) * 8)];
            }
#pragma unroll
            for (int i = 0; i < 4; ++i)
#pragma unroll
                for (int j = 0; j < 4; ++j)
                    acc[i][j] = __builtin_amdgcn_mfma_f32_16x16x32_bf16(af[i], bfr[j], acc[i][j], 0, 0, 0);
        }
        __syncthreads();
    }

    // C -> LDS (bf16, matches old Qb round-trip precision)
    int r4 = (lane >> 4) * 4;
#pragma unroll
    for (int j = 0; j < 4; ++j) {
        int col = wn + j * 16 + l15;
        float bvv = bias[col];
#pragma unroll
        for (int i = 0; i < 4; ++i)
#pragma unroll
            for (int r = 0; r < 4; ++r)
                Cls[(wm + i * 16 + r4 + r) * 260 + col] = f2bf(acc[i][j][r] + bvv);
    }
    __syncthreads();

    // Residual + LN per row; wave w handles rows w*16 .. w*16+15.
    int c4 = lane * 4;
    float4 gw = *(const float4*)&g[c4];
    float4 bw = *(const float4*)&b[c4];
#pragma unroll 2
    for (int rw = 0; rw < 16; ++rw) {
        int row = wave * 16 + rw;
        size_t gidx = (size_t)(bm + row) * 256 + c4;
        bf16x4 xb = *(const bf16x4*)(Xb + gidx);
        bf16x4 cb = *(const bf16x4*)&Cls[row * 260 + c4];
        float4 v;
        v.x = (float)xb[0] + (float)cb[0];
        v.y = (float)xb[1] + (float)cb[1];
        v.z = (float)xb[2] + (float)cb[2];
        v.w = (float)xb[3] + (float)cb[3];
        float s  = v.x + v.y + v.z + v.w;
        float sq = v.x * v.x + v.y * v.y + v.z * v.z + v.w * v.w;
#pragma unroll
        for (int off = 32; off > 0; off >>= 1) {
            s  += __shfl_xor(s,  off);
            sq += __shfl_xor(sq, off);
        }
        float mean = s * (1.f / 256.f);
        float var  = sq * (1.f / 256.f) - mean * mean;
        float rstd = rsqrtf(var + 1e-5f);
        bf16x4 ob;
        ob[0] = f2bf((v.x - mean) * rstd * gw.x + bw.x);
        ob[1] = f2bf((v.y - mean) * rstd * gw.y + bw.y);
        ob[2] = f2bf((v.z - mean) * rstd * gw.z + bw.z);
        ob[3] = f2bf((v.w - mean) * rstd * gw.w + bw.w);
        *(bf16x4*)(Xb + gidx) = ob;
    }
}

// ---------------------------------------------------------------------------
// KV prep v3: grid (32 sp, 64 nh), 256 thr = 4 waves.
// ---------------------------------------------------------------------------
__global__ __launch_bounds__(256) void kv_prep_part(const bf16* __restrict__ Kb,
                                                    const bf16* __restrict__ Vb,
                                                    float* __restrict__ Pkv,
                                                    float* __restrict__ Pks) {
    __shared__ float Ks[128][32];
    __shared__ float Vs[128][32];
    int sp = blockIdx.x;          // 0..31
    int nh = blockIdx.y;          // 0..63
    int n = nh >> 3, h = nh & 7;
    int tid = threadIdx.x;
    int wave = tid >> 6, lane = tid & 63;
    int mg = lane >> 3;           // 0..7  (4 m each)
    int dg = lane & 7;            // 0..7  (4 d each)
    size_t base = ((size_t)n * 4096 + sp * 128) * 256 + h * 32;

#pragma unroll
    for (int p = 0; p < 2; ++p) {
        int r = p * 64 + (tid >> 2);
        int c = (tid & 3) * 8;
        bf16x8 k8 = *(const bf16x8*)(Kb + base + (size_t)r * 256 + c);
        bf16x8 v8 = *(const bf16x8*)(Vb + base + (size_t)r * 256 + c);
#pragma unroll
        for (int u = 0; u < 8; ++u) { Ks[r][c + u] = (float)k8[u]; Vs[r][c + u] = (float)v8[u]; }
    }
    __syncthreads();

    float acc[4][4] = {};
    float ks4[4] = {};
    int s0 = wave * 32;
    for (int s = s0; s < s0 + 32; ++s) {
        float4 kq = *(float4*)&Ks[s][dg * 4];
        float4 vq = *(float4*)&Vs[s][mg * 4];
        ks4[0] += kq.x; ks4[1] += kq.y; ks4[2] += kq.z; ks4[3] += kq.w;
        acc[0][0] += vq.x * kq.x; acc[0][1] += vq.x * kq.y; acc[0][2] += vq.x * kq.z; acc[0][3] += vq.x * kq.w;
        acc[1][0] += vq.y * kq.x; acc[1][1] += vq.y * kq.y; acc[1][2] += vq.y * kq.z; acc[1][3] += vq.y * kq.w;
        acc[2][0] += vq.z * kq.x; acc[2][1] += vq.z * kq.y; acc[2][2] += vq.z * kq.z; acc[2][3] += vq.z * kq.w;
        acc[3][0] += vq.w * kq.x; acc[3][1] += vq.w * kq.y; acc[3][2] += vq.w * kq.z; acc[3][3] += vq.w * kq.w;
    }
    __syncthreads();

    float* R  = &Ks[0][0];
    float* RS = &Vs[0][0];
#pragma unroll
    for (int mi = 0; mi < 4; ++mi)
#pragma unroll
        for (int dj = 0; dj < 4; ++dj)
            R[wave * 1024 + (mg * 4 + mi) * 32 + dg * 4 + dj] = acc[mi][dj];
    if (mg == 0)
#pragma unroll
        for (int dj = 0; dj < 4; ++dj) RS[wave * 32 + dg * 4 + dj] = ks4[dj];
    __syncthreads();

    int e = tid * 4;
    float4 o0 = *(float4*)&R[e];
    float4 o1 = *(float4*)&R[1024 + e];
    float4 o2 = *(float4*)&R[2048 + e];
    float4 o3 = *(float4*)&R[3072 + e];
    float4 o = make_float4(o0.x + o1.x + o2.x + o3.x, o0.y + o1.y + o2.y + o3.y,
                           o0.z + o1.z + o2.z + o3.z, o0.w + o1.w + o2.w + o3.w);
    *(float4*)&Pkv[((size_t)nh * 32 + sp) * 1024 + e] = o;
    if (tid < 32)
        Pks[((size_t)nh * 32 + sp) * 32 + tid] = RS[tid] + RS[32 + tid] + RS[64 + tid] + RS[96 + tid];
}

// grid (64 nh, 4 quarters), 64 threads (1 wave) — 256 blocks for parallelism.
__global__ __launch_bounds__(64) void kv_reduce(const float* __restrict__ Pkv,
                                                const float* __restrict__ Pks,
                                                float* __restrict__ KV,
                                                float* __restrict__ Ksum) {
    int nh = blockIdx.x;
    int q = blockIdx.y;
    int e = (q * 64 + threadIdx.x) * 4;
    float4 s = make_float4(0.f, 0.f, 0.f, 0.f);
    for (int sp = 0; sp < 32; ++sp) {
        float4 p = *(const float4*)&Pkv[((size_t)nh * 32 + sp) * 1024 + e];
        s.x += p.x; s.y += p.y; s.z += p.z; s.w += p.w;
    }
    *(float4*)&KV[(size_t)nh * 1024 + e] = s;
    if (q == 0 && threadIdx.x < 32) {
        float ss = 0.f;
        for (int sp = 0; sp < 32; ++sp) ss += Pks[((size_t)nh * 32 + sp) * 32 + threadIdx.x];
        Ksum[nh * 32 + threadIdx.x] = ss;
    }
}

// ---------------------------------------------------------------------------
// Attention apply: 32 tokens/block, Q (bf16) tile -> LDS f32, KV row in regs.
// ---------------------------------------------------------------------------
__global__ __launch_bounds__(256) void attn_apply(const bf16* __restrict__ Qb,
                                                  const float* __restrict__ KV,
                                                  const float* __restrict__ Ksum,
                                                  bf16* __restrict__ B) {
    __shared__ float Qs[32][260];
    __shared__ float Zs[32][8];
    int bx = blockIdx.x;
    int n = bx >> 7;
    int tok0 = (bx & 127) << 5;
    int tid = threadIdx.x;

    const bf16* qsrc = Qb + ((size_t)(n * 4096 + tok0)) * 256;
#pragma unroll
    for (int kk = 0; kk < 4; ++kk) {
        int e8 = tid + kk * 256;
        bf16x8 v = *(const bf16x8*)(qsrc + (size_t)e8 * 8);
        int t = e8 >> 5, c8 = e8 & 31;
#pragma unroll
        for (int u = 0; u < 8; ++u) Qs[t][c8 * 8 + u] = (float)v[u];
    }

    int h = tid >> 5, m = tid & 31;
    float kvr[32];
    const float* kvp = KV + (size_t)(n * 8 + h) * 1024 + m * 32;
#pragma unroll
    for (int c = 0; c < 8; ++c) *(float4*)&kvr[c * 4] = *(const float4*)(kvp + c * 4);
    __syncthreads();

    {
        int tz = tid >> 3, hz = tid & 7;
        const float* ksp = Ksum + n * 256 + hz * 32;
        float z = 0.f;
#pragma unroll
        for (int c = 0; c < 8; ++c) {
            float4 q = *(float4*)&Qs[tz][hz * 32 + c * 4];
            float4 k = *(const float4*)(ksp + c * 4);
            z += q.x * k.x + q.y * k.y + q.z * k.z + q.w * k.w;
        }
        Zs[tz][hz] = 1.f / (z + 1e-6f);
    }
    __syncthreads();

    bf16* outp = B + ((size_t)(n * 4096 + tok0)) * 256 + tid;
#pragma unroll 2
    for (int t = 0; t < 32; ++t) {
        float acc = 0.f;
#pragma unroll
        for (int c = 0; c < 8; ++c) {
            float4 q = *(float4*)&Qs[t][h * 32 + c * 4];
            acc += q.x * kvr[c * 4 + 0] + q.y * kvr[c * 4 + 1]
                 + q.z * kvr[c * 4 + 2] + q.w * kvr[c * 4 + 3];
        }
        outp[(size_t)t * 256] = f2bf(acc * Zs[t][h]);
    }
}

// ---------------------------------------------------------------------------
// Store: Xb[b,t,c] bf16 -> out[b,c,t] f32
// ---------------------------------------------------------------------------
__global__ __launch_bounds__(1024) void store_kernel(const bf16* __restrict__ Xb,
                                                     float* __restrict__ out) {
    __shared__ float tile[32][33];
    int b = blockIdx.z;
    int t0 = blockIdx.x * 32, c0 = blockIdx.y * 32;
    tile[threadIdx.y][threadIdx.x] =
        (float)Xb[((size_t)b * 4096 + t0 + threadIdx.y) * 256 + c0 + threadIdx.x];
    __syncthreads();
    out[((size_t)b * 256 + c0 + threadIdx.y) * 4096 + t0 + threadIdx.x] =
        tile[threadIdx.x][threadIdx.y];
}

// ---------------------------------------------------------------------------
extern "C" void kernel_launch(void* const* d_in, const int* in_sizes, int n_in,
                              void* d_out, int out_size, void* d_ws, size_t ws_size,
                              hipStream_t stream) {
    const float* ref  = (const float*)d_in[0];
    const float* srcf = (const float*)d_in[1];
    const float* Wq = (const float*)d_in[2];
    const float* bq = (const float*)d_in[3];
    const float* Wk = (const float*)d_in[4];
    const float* bk = (const float*)d_in[5];
    const float* Wv = (const float*)d_in[6];
    const float* bv = (const float*)d_in[7];
    const float* Wo = (const float*)d_in[8];
    const float* bo = (const float*)d_in[9];
    const float* W1 = (const float*)d_in[10];
    const float* b1 = (const float*)d_in[11];
    const float* W2 = (const float*)d_in[12];
    const float* b2 = (const float*)d_in[13];
    const float* g1 = (const float*)d_in[14];
    const float* be1 = (const float*)d_in[15];
    const float* g2 = (const float*)d_in[16];
    const float* be2 = (const float*)d_in[17];

    const size_t SZ = (size_t)8 * 4096 * 256;
    float* ws  = (float*)d_ws;
    float* KVb = ws;                          // 65536 f32
    float* Ksb = KVb + 65536;                 // 2048 f32
    float* Pkv = Ksb + 2048;                  // 2,097,152 f32 (64 nh x 32 sp x 1024)
    float* Pks = Pkv + 2097152;               // 65536 f32
    bf16*  Wt  = (bf16*)(Pks + 65536);        // 2,097,152 bf16
    bf16*  Xb  = Wt + 2097152;                // SZ bf16 (residual stream)
    bf16*  P2b = Xb + SZ;                     // SZ bf16 (original features, batch-swapped)
    bf16*  Qb  = P2b + SZ;                    // SZ bf16
    // K/V live in d_out (exact 2*SZ bf16 fit); dead before store_kernel runs.
    bf16*  Kb  = (bf16*)d_out;
    bf16*  Vb  = Kb + SZ;
    bf16*  Bb  = Kb;                          // alias: K dead after kv_prep
    bf16*  Hb  = Kb;                          // alias: FFN hidden spans Kb+Vb

    wt_conv<<<dim3(16, 16, 24), dim3(32, 32), 0, stream>>>(Wq, Wk, Wv, Wo, W1, W2, Wt);
    encode_kernel<<<dim3(128, 8, 8), dim3(32, 32), 0, stream>>>(ref, srcf, Xb, P2b);

    for (int L = 0; L < 4; ++L) {
        const bf16* WtL = Wt + (size_t)L * 524288;
        const bf16* Akv = (L & 1) ? P2b : Xb;
        gemm_qkv<<<dim3(6, 256), 256, 0, stream>>>(Xb, Akv, WtL,
                                                   bq + L * 256, bk + L * 256, bv + L * 256,
                                                   Qb, Kb, Vb);
        kv_prep_part<<<dim3(32, 64), 256, 0, stream>>>(Kb, Vb, Pkv, Pks);
        kv_reduce<<<dim3(64, 4), 64, 0, stream>>>(Pkv, Pks, KVb, Ksb);
        attn_apply<<<1024, 256, 0, stream>>>(Qb, KVb, Ksb, Bb);
        // O-proj + residual + LN1 fused
        gemm_ln<<<256, 512, 0, stream>>>(Bb, WtL + 196608, bo + L * 256, Xb,
                                         g1 + L * 256, be1 + L * 256, 256);
        // FFN1 (relu) -> Hb
        gemm_mfma<1><<<dim3(4, 256), 256, 0, stream>>>(Xb, WtL + 262144, b1 + L * 512, Hb, 512, 256);
        // FFN2 + residual + LN2 fused
        gemm_ln<<<256, 512, 0, stream>>>(Hb, WtL + 393216, b2 + L * 256, Xb,
                                         g2 + L * 256, be2 + L * 256, 512);
    }

    store_kernel<<<dim3(128, 8, 8), dim3(32, 32), 0, stream>>>(Xb, (float*)d_out);
}

// Round 3
// 673.858 us; speedup vs baseline: 1.0825x; 1.0254x over previous
//
#include <hip/hip_runtime.h>
#include <hip/hip_bf16.h>

typedef __bf16 bf16;
typedef __attribute__((ext_vector_type(8))) __bf16 bf16x8;
typedef __attribute__((ext_vector_type(4))) __bf16 bf16x4;
typedef __attribute__((ext_vector_type(4))) float f32x4;

__device__ __forceinline__ bf16 f2bf(float f) { return (bf16)f; }

// async global->LDS, 16B per lane. LDS dest must be uniform-base + lane*16.
__device__ __forceinline__ void async_cp16(const void* g, void* l) {
    __builtin_amdgcn_global_load_lds(
        (const __attribute__((address_space(1))) unsigned int*)g,
        (__attribute__((address_space(3))) unsigned int*)l, 16, 0, 0);
}

// ---------------------------------------------------------------------------
// Positional encoding value for channel c, token t (t = h*64 + w)
// ---------------------------------------------------------------------------
__device__ __forceinline__ float pe_val(int c, int t) {
    int h = t >> 6, w = t & 63;
    int i = c >> 2, j = c & 3;
    float div = expf(-0.14391156831212787f * (float)i);
    float arg = ((j < 2) ? (float)w : (float)h) * div;
    return (j & 1) ? cosf(arg) : sinf(arg);
}

// ---------------------------------------------------------------------------
// Encode: feat (4,256,4096) f32 -> Xb[b,t,c] bf16, P2b bf16 (PE added).
// ---------------------------------------------------------------------------
__global__ __launch_bounds__(1024) void encode_kernel(const float* __restrict__ ref,
                                                      const float* __restrict__ src,
                                                      bf16* __restrict__ Xb,
                                                      bf16* __restrict__ P2b) {
    __shared__ float tile[32][33];
    int n = blockIdx.z >> 1, sel = blockIdx.z & 1;
    const float* f = sel ? src : ref;
    int t = blockIdx.x * 32 + threadIdx.x;
    int c = blockIdx.y * 32 + threadIdx.y;
    float v = f[((size_t)n * 256 + c) * 4096 + t] + pe_val(c, t);
    tile[threadIdx.y][threadIdx.x] = v;
    __syncthreads();
    int tt = blockIdx.x * 32 + threadIdx.y;
    int cc = blockIdx.y * 32 + threadIdx.x;
    float o = tile[threadIdx.x][threadIdx.y];
    int bx = sel ? 4 + n : n;
    int bp = sel ? n : 4 + n;
    Xb [((size_t)bx * 4096 + tt) * 256 + cc] = f2bf(o);
    P2b[((size_t)bp * 4096 + tt) * 256 + cc] = f2bf(o);
}

// ---------------------------------------------------------------------------
// Weight transpose+convert: W[K,N] f32 -> Wt[N,K] bf16, all 24 mats, 1 launch
// ---------------------------------------------------------------------------
__global__ __launch_bounds__(1024) void wt_conv(const float* __restrict__ Wq, const float* __restrict__ Wk,
                                                const float* __restrict__ Wv, const float* __restrict__ Wo,
                                                const float* __restrict__ W1, const float* __restrict__ W2,
                                                bf16* __restrict__ Wt) {
    __shared__ float t[32][33];
    int z = blockIdx.z, L = z / 6, m = z - L * 6;
    const float* src; int K, N, doff;
    if      (m == 0) { src = Wq + L * 65536;  K = 256; N = 256; doff = 0; }
    else if (m == 1) { src = Wk + L * 65536;  K = 256; N = 256; doff = 65536; }
    else if (m == 2) { src = Wv + L * 65536;  K = 256; N = 256; doff = 131072; }
    else if (m == 3) { src = Wo + L * 65536;  K = 256; N = 256; doff = 196608; }
    else if (m == 4) { src = W1 + L * 131072; K = 256; N = 512; doff = 262144; }
    else             { src = W2 + L * 131072; K = 512; N = 256; doff = 393216; }
    int n0 = blockIdx.x * 32, k0 = blockIdx.y * 32;
    if (n0 >= N || k0 >= K) return;
    t[threadIdx.y][threadIdx.x] = src[(size_t)(k0 + threadIdx.y) * N + n0 + threadIdx.x];
    __syncthreads();
    bf16* dst = Wt + (size_t)L * 524288 + doff;
    dst[(size_t)(n0 + threadIdx.y) * K + k0 + threadIdx.x] = f2bf(t[threadIdx.x][threadIdx.y]);
}

// ---------------------------------------------------------------------------
// Fused QKV GEMM (unchanged)
// ---------------------------------------------------------------------------
__global__ __launch_bounds__(256) void gemm_qkv(const bf16* __restrict__ Aq,
                                                const bf16* __restrict__ Akv,
                                                const bf16* __restrict__ Wt,
                                                const float* __restrict__ bq,
                                                const float* __restrict__ bk,
                                                const float* __restrict__ bv,
                                                bf16* __restrict__ Q,
                                                bf16* __restrict__ Ko,
                                                bf16* __restrict__ V) {
    __shared__ bf16 Als[128 * 64];
    __shared__ bf16 Bls[128 * 64];
    int tid = threadIdx.x;
    int wave = tid >> 6, lane = tid & 63;
    int bm = blockIdx.y * 128, bn = blockIdx.x * 128;
    int wm = (wave >> 1) * 64, wn = (wave & 1) * 64;
    int l15 = lane & 15, g = lane >> 4;
    const int K = 256;

    int seg = bn >> 8, cloc = bn & 255;
    const bf16* A = seg == 0 ? Aq : Akv;
    const float* bias = seg == 0 ? bq : (seg == 1 ? bk : bv);
    bf16* Out = seg == 0 ? Q : (seg == 1 ? Ko : V);
    bool do_elu = seg < 2;

    f32x4 acc[4][4] = {};

    for (int k0 = 0; k0 < K; k0 += 64) {
#pragma unroll
        for (int r = 0; r < 4; ++r) {
            int Lc = r * 256 + tid;
            int row = Lc >> 3, cs = Lc & 7;
            int gc = cs ^ (row & 7);
            async_cp16(A  + (size_t)(bm + row) * K + k0 + gc * 8, &Als[Lc * 8]);
            async_cp16(Wt + (size_t)(bn + row) * K + k0 + gc * 8, &Bls[Lc * 8]);
        }
        __syncthreads();
#pragma unroll
        for (int ks = 0; ks < 2; ++ks) {
            bf16x8 af[4], bfr[4];
#pragma unroll
            for (int i = 0; i < 4; ++i) {
                int row = wm + i * 16 + l15;
                int c = ks * 4 + g;
                af[i] = *(bf16x8*)&Als[row * 64 + ((c ^ (row & 7)) * 8)];
            }
#pragma unroll
            for (int j = 0; j < 4; ++j) {
                int row = wn + j * 16 + l15;
                int c = ks * 4 + g;
                bfr[j] = *(bf16x8*)&Bls[row * 64 + ((c ^ (row & 7)) * 8)];
            }
#pragma unroll
            for (int i = 0; i < 4; ++i)
#pragma unroll
                for (int j = 0; j < 4; ++j)
                    acc[i][j] = __builtin_amdgcn_mfma_f32_16x16x32_bf16(af[i], bfr[j], acc[i][j], 0, 0, 0);
        }
        __syncthreads();
    }

    int r4 = (lane >> 4) * 4;
#pragma unroll
    for (int i = 0; i < 4; ++i) {
#pragma unroll
        for (int j = 0; j < 4; ++j) {
            int cj = cloc + wn + j * 16 + l15;
            float bvv = bias[cj];
#pragma unroll
            for (int r = 0; r < 4; ++r) {
                int row = bm + wm + i * 16 + r4 + r;
                float v = acc[i][j][r] + bvv;
                if (do_elu) v = v > 0.f ? v + 1.f : expf(v);
                Out[(size_t)row * 256 + cj] = f2bf(v);
            }
        }
    }
}

// ---------------------------------------------------------------------------
// MFMA GEMM (FFN1 only): C[M,N] bf16 = relu(A @ Wt^T + bias)
// ---------------------------------------------------------------------------
template <int RELU>
__global__ __launch_bounds__(256) void gemm_mfma(const bf16* __restrict__ A,
                                                 const bf16* __restrict__ Wt,
                                                 const float* __restrict__ bias,
                                                 bf16* __restrict__ C,
                                                 int N, int K) {
    __shared__ bf16 Als[128 * 64];
    __shared__ bf16 Bls[128 * 64];
    int tid = threadIdx.x;
    int wave = tid >> 6, lane = tid & 63;
    int bm = blockIdx.y * 128, bn = blockIdx.x * 128;
    int wm = (wave >> 1) * 64, wn = (wave & 1) * 64;
    int l15 = lane & 15, g = lane >> 4;

    f32x4 acc[4][4] = {};

    for (int k0 = 0; k0 < K; k0 += 64) {
#pragma unroll
        for (int r = 0; r < 4; ++r) {
            int Lc = r * 256 + tid;
            int row = Lc >> 3, cs = Lc & 7;
            int gc = cs ^ (row & 7);
            async_cp16(A  + (size_t)(bm + row) * K + k0 + gc * 8, &Als[Lc * 8]);
            async_cp16(Wt + (size_t)(bn + row) * K + k0 + gc * 8, &Bls[Lc * 8]);
        }
        __syncthreads();
#pragma unroll
        for (int ks = 0; ks < 2; ++ks) {
            bf16x8 af[4], bfr[4];
#pragma unroll
            for (int i = 0; i < 4; ++i) {
                int row = wm + i * 16 + l15;
                int c = ks * 4 + g;
                af[i] = *(bf16x8*)&Als[row * 64 + ((c ^ (row & 7)) * 8)];
            }
#pragma unroll
            for (int j = 0; j < 4; ++j) {
                int row = wn + j * 16 + l15;
                int c = ks * 4 + g;
                bfr[j] = *(bf16x8*)&Bls[row * 64 + ((c ^ (row & 7)) * 8)];
            }
#pragma unroll
            for (int i = 0; i < 4; ++i)
#pragma unroll
                for (int j = 0; j < 4; ++j)
                    acc[i][j] = __builtin_amdgcn_mfma_f32_16x16x32_bf16(af[i], bfr[j], acc[i][j], 0, 0, 0);
        }
        __syncthreads();
    }

    int r4 = (lane >> 4) * 4;
#pragma unroll
    for (int i = 0; i < 4; ++i) {
#pragma unroll
        for (int j = 0; j < 4; ++j) {
            int col = bn + wn + j * 16 + l15;
            float bvv = bias[col];
#pragma unroll
            for (int r = 0; r < 4; ++r) {
                int row = bm + wm + i * 16 + r4 + r;
                float v = acc[i][j][r] + bvv;
                if (RELU) v = fmaxf(v, 0.f);
                C[(size_t)row * N + col] = f2bf(v);
            }
        }
    }
}

// ---------------------------------------------------------------------------
// Fused GEMM (N=256) + residual + LayerNorm epilogue (FFN2 path, unchanged)
// ---------------------------------------------------------------------------
__global__ __launch_bounds__(512) void gemm_ln(const bf16* __restrict__ A,
                                               const bf16* __restrict__ Wt,
                                               const float* __restrict__ bias,
                                               bf16* __restrict__ Xb,
                                               const float* __restrict__ g,
                                               const float* __restrict__ b,
                                               int K) {
    __shared__ __align__(16) char smem[128 * 260 * 2];  // 66560 B
    bf16* Als = (bf16*)smem;            // [128][64]  16 KB (during K loop)
    bf16* Bls = (bf16*)(smem + 16384);  // [256][64]  32 KB (during K loop)
    bf16* Cls = (bf16*)smem;            // [128][260] after K loop

    int tid = threadIdx.x;
    int wave = tid >> 6, lane = tid & 63;
    int bm = blockIdx.x * 128;
    int wm = (wave >> 2) * 64, wn = (wave & 3) * 64;
    int l15 = lane & 15, gg = lane >> 4;

    f32x4 acc[4][4] = {};

    for (int k0 = 0; k0 < K; k0 += 64) {
#pragma unroll
        for (int r = 0; r < 2; ++r) {   // A tile: 128x64
            int Lc = r * 512 + tid;
            int row = Lc >> 3, cs = Lc & 7;
            int gc = cs ^ (row & 7);
            async_cp16(A + (size_t)(bm + row) * K + k0 + gc * 8, &Als[Lc * 8]);
        }
#pragma unroll
        for (int r = 0; r < 4; ++r) {   // B tile: 256x64
            int Lc = r * 512 + tid;
            int row = Lc >> 3, cs = Lc & 7;
            int gc = cs ^ (row & 7);
            async_cp16(Wt + (size_t)row * K + k0 + gc * 8, &Bls[Lc * 8]);
        }
        __syncthreads();
#pragma unroll
        for (int ks = 0; ks < 2; ++ks) {
            bf16x8 af[4], bfr[4];
#pragma unroll
            for (int i = 0; i < 4; ++i) {
                int row = wm + i * 16 + l15;
                int c = ks * 4 + gg;
                af[i] = *(bf16x8*)&Als[row * 64 + ((c ^ (row & 7)) * 8)];
            }
#pragma unroll
            for (int j = 0; j < 4; ++j) {
                int row = wn + j * 16 + l15;
                int c = ks * 4 + gg;
                bfr[j] = *(bf16x8*)&Bls[row * 64 + ((c ^ (row & 7)) * 8)];
            }
#pragma unroll
            for (int i = 0; i < 4; ++i)
#pragma unroll
                for (int j = 0; j < 4; ++j)
                    acc[i][j] = __builtin_amdgcn_mfma_f32_16x16x32_bf16(af[i], bfr[j], acc[i][j], 0, 0, 0);
        }
        __syncthreads();
    }

    int r4 = (lane >> 4) * 4;
#pragma unroll
    for (int j = 0; j < 4; ++j) {
        int col = wn + j * 16 + l15;
        float bvv = bias[col];
#pragma unroll
        for (int i = 0; i < 4; ++i)
#pragma unroll
            for (int r = 0; r < 4; ++r)
                Cls[(wm + i * 16 + r4 + r) * 260 + col] = f2bf(acc[i][j][r] + bvv);
    }
    __syncthreads();

    int c4 = lane * 4;
    float4 gw = *(const float4*)&g[c4];
    float4 bw = *(const float4*)&b[c4];
#pragma unroll 2
    for (int rw = 0; rw < 16; ++rw) {
        int row = wave * 16 + rw;
        size_t gidx = (size_t)(bm + row) * 256 + c4;
        bf16x4 xb = *(const bf16x4*)(Xb + gidx);
        bf16x4 cb = *(const bf16x4*)&Cls[row * 260 + c4];
        float4 v;
        v.x = (float)xb[0] + (float)cb[0];
        v.y = (float)xb[1] + (float)cb[1];
        v.z = (float)xb[2] + (float)cb[2];
        v.w = (float)xb[3] + (float)cb[3];
        float s  = v.x + v.y + v.z + v.w;
        float sq = v.x * v.x + v.y * v.y + v.z * v.z + v.w * v.w;
#pragma unroll
        for (int off = 32; off > 0; off >>= 1) {
            s  += __shfl_xor(s,  off);
            sq += __shfl_xor(sq, off);
        }
        float mean = s * (1.f / 256.f);
        float var  = sq * (1.f / 256.f) - mean * mean;
        float rstd = rsqrtf(var + 1e-5f);
        bf16x4 ob;
        ob[0] = f2bf((v.x - mean) * rstd * gw.x + bw.x);
        ob[1] = f2bf((v.y - mean) * rstd * gw.y + bw.y);
        ob[2] = f2bf((v.z - mean) * rstd * gw.z + bw.z);
        ob[3] = f2bf((v.w - mean) * rstd * gw.w + bw.w);
        *(bf16x4*)(Xb + gidx) = ob;
    }
}

// ---------------------------------------------------------------------------
// Fused attention + O-projection + residual + LN1.
// Block = 128 tokens, 512 threads (8 waves). Grid 256.
// Phase 1 (x4 sub-batches of 32 tokens): Q->LDS f32, Z from Ksum, per-col
//   f32 VALU dot with KV row (regs); result written bf16 straight into a
//   swizzled LDS A-tile [4][128][64] (same XOR scheme as GEMM staging).
// Phase 2: standard MFMA K-loop, A from LDS, Wo staged per k-step.
// Phase 3: gemm_ln epilogue (residual + LN into Xb).
// LDS: region0 (66560 B) time-shared by Qs f32[32][260] / Wls / Cls;
//      region1 (65536 B) = swizzled A-tile. Total 132 KB + Zs.
// Numerics identical to old attn_apply + gemm_ln (attn out through bf16).
// ---------------------------------------------------------------------------
__global__ __launch_bounds__(512) void attn_oln(const bf16* __restrict__ Qb,
                                                const float* __restrict__ KV,
                                                const float* __restrict__ Ksum,
                                                const bf16* __restrict__ Wt,
                                                const float* __restrict__ bias,
                                                bf16* __restrict__ Xb,
                                                const float* __restrict__ g,
                                                const float* __restrict__ b) {
    __shared__ __align__(16) char smem[132096];
    __shared__ float Zs[32][8];
    float* Qs  = (float*)smem;               // [32][260] f32 (phase 1)
    bf16*  Wls = (bf16*)smem;                // [256*64]  (phase 2)
    bf16*  Cls = (bf16*)smem;                // [128][260] (phase 3)
    bf16*  Bt  = (bf16*)(smem + 66560);      // [4][128][64] swizzled A-tile

    int tid = threadIdx.x;
    int r0 = blockIdx.x * 128;               // global row (= n*4096 + token)
    int n = r0 >> 12;

    // per-thread KV row (f32): col c -> head h, m
    int c = tid & 255, tg = tid >> 8;
    int h = c >> 5, m = c & 31;
    float kvr[32];
    const float* kvp = KV + (size_t)(n * 8 + h) * 1024 + m * 32;
#pragma unroll
    for (int q4 = 0; q4 < 8; ++q4) *(float4*)&kvr[q4 * 4] = *(const float4*)(kvp + q4 * 4);

    int col8 = (c >> 3) & 7, elem = c & 7, slice = c >> 6;

    for (int it = 0; it < 4; ++it) {
        int t0 = it * 32;
        const bf16* qsrc = Qb + (size_t)(r0 + t0) * 256;
#pragma unroll
        for (int kk = 0; kk < 2; ++kk) {
            int e8 = kk * 512 + tid;
            bf16x8 v = *(const bf16x8*)(qsrc + (size_t)e8 * 8);
            int t = e8 >> 5, c8 = e8 & 31;
#pragma unroll
            for (int u = 0; u < 8; ++u) Qs[t * 260 + c8 * 8 + u] = (float)v[u];
        }
        __syncthreads();
        if (tid < 256) {
            int tz = tid >> 3, hz = tid & 7;
            const float* ksp = Ksum + n * 256 + hz * 32;
            float z = 0.f;
#pragma unroll
            for (int q4 = 0; q4 < 8; ++q4) {
                float4 qv = *(float4*)&Qs[tz * 260 + hz * 32 + q4 * 4];
                float4 kq = *(const float4*)(ksp + q4 * 4);
                z += qv.x * kq.x + qv.y * kq.y + qv.z * kq.z + qv.w * kq.w;
            }
            Zs[tz][hz] = 1.f / (z + 1e-6f);
        }
        __syncthreads();
#pragma unroll 2
        for (int tt = 0; tt < 16; ++tt) {
            int t = tg * 16 + tt;
            float acc = 0.f;
#pragma unroll
            for (int q4 = 0; q4 < 8; ++q4) {
                float4 qv = *(float4*)&Qs[t * 260 + h * 32 + q4 * 4];
                acc += qv.x * kvr[q4 * 4 + 0] + qv.y * kvr[q4 * 4 + 1]
                     + qv.z * kvr[q4 * 4 + 2] + qv.w * kvr[q4 * 4 + 3];
            }
            int row = t0 + t;
            Bt[slice * 8192 + row * 64 + ((col8 ^ (row & 7)) * 8) + elem] =
                f2bf(acc * Zs[t][h]);
        }
        __syncthreads();
    }

    // Phase 2: C[128][256] = Bt @ Wo^T
    int wave = tid >> 6, lane = tid & 63;
    int wm = (wave >> 2) * 64, wn = (wave & 3) * 64;
    int l15 = lane & 15, gg = lane >> 4;
    f32x4 acc[4][4] = {};

    for (int k0 = 0; k0 < 256; k0 += 64) {
#pragma unroll
        for (int r = 0; r < 4; ++r) {   // Wo tile: 256x64
            int Lc = r * 512 + tid;
            int row = Lc >> 3, cs = Lc & 7;
            int gc = cs ^ (row & 7);
            async_cp16(Wt + (size_t)row * 256 + k0 + gc * 8, &Wls[Lc * 8]);
        }
        __syncthreads();
        const bf16* Asl = Bt + (k0 >> 6) * 8192;
#pragma unroll
        for (int ks = 0; ks < 2; ++ks) {
            bf16x8 af[4], bfr[4];
#pragma unroll
            for (int i = 0; i < 4; ++i) {
                int row = wm + i * 16 + l15;
                int cc = ks * 4 + gg;
                af[i] = *(bf16x8*)&Asl[row * 64 + ((cc ^ (row & 7)) * 8)];
            }
#pragma unroll
            for (int j = 0; j < 4; ++j) {
                int row = wn + j * 16 + l15;
                int cc = ks * 4 + gg;
                bfr[j] = *(bf16x8*)&Wls[row * 64 + ((cc ^ (row & 7)) * 8)];
            }
#pragma unroll
            for (int i = 0; i < 4; ++i)
#pragma unroll
                for (int j = 0; j < 4; ++j)
                    acc[i][j] = __builtin_amdgcn_mfma_f32_16x16x32_bf16(af[i], bfr[j], acc[i][j], 0, 0, 0);
        }
        __syncthreads();
    }

    // Phase 3: C -> LDS, residual + LN into Xb (gemm_ln epilogue)
    int r4 = (lane >> 4) * 4;
#pragma unroll
    for (int j = 0; j < 4; ++j) {
        int col = wn + j * 16 + l15;
        float bvv = bias[col];
#pragma unroll
        for (int i = 0; i < 4; ++i)
#pragma unroll
            for (int r = 0; r < 4; ++r)
                Cls[(wm + i * 16 + r4 + r) * 260 + col] = f2bf(acc[i][j][r] + bvv);
    }
    __syncthreads();

    int c4 = lane * 4;
    float4 gw = *(const float4*)&g[c4];
    float4 bw = *(const float4*)&b[c4];
#pragma unroll 2
    for (int rw = 0; rw < 16; ++rw) {
        int row = wave * 16 + rw;
        size_t gidx = (size_t)(r0 + row) * 256 + c4;
        bf16x4 xb = *(const bf16x4*)(Xb + gidx);
        bf16x4 cb = *(const bf16x4*)&Cls[row * 260 + c4];
        float4 v;
        v.x = (float)xb[0] + (float)cb[0];
        v.y = (float)xb[1] + (float)cb[1];
        v.z = (float)xb[2] + (float)cb[2];
        v.w = (float)xb[3] + (float)cb[3];
        float s  = v.x + v.y + v.z + v.w;
        float sq = v.x * v.x + v.y * v.y + v.z * v.z + v.w * v.w;
#pragma unroll
        for (int off = 32; off > 0; off >>= 1) {
            s  += __shfl_xor(s,  off);
            sq += __shfl_xor(sq, off);
        }
        float mean = s * (1.f / 256.f);
        float var  = sq * (1.f / 256.f) - mean * mean;
        float rstd = rsqrtf(var + 1e-5f);
        bf16x4 ob;
        ob[0] = f2bf((v.x - mean) * rstd * gw.x + bw.x);
        ob[1] = f2bf((v.y - mean) * rstd * gw.y + bw.y);
        ob[2] = f2bf((v.z - mean) * rstd * gw.z + bw.z);
        ob[3] = f2bf((v.w - mean) * rstd * gw.w + bw.w);
        *(bf16x4*)(Xb + gidx) = ob;
    }
}

// ---------------------------------------------------------------------------
// KV prep v3: grid (32 sp, 64 nh), 256 thr = 4 waves. (unchanged)
// ---------------------------------------------------------------------------
__global__ __launch_bounds__(256) void kv_prep_part(const bf16* __restrict__ Kb,
                                                    const bf16* __restrict__ Vb,
                                                    float* __restrict__ Pkv,
                                                    float* __restrict__ Pks) {
    __shared__ float Ks[128][32];
    __shared__ float Vs[128][32];
    int sp = blockIdx.x;          // 0..31
    int nh = blockIdx.y;          // 0..63
    int n = nh >> 3, h = nh & 7;
    int tid = threadIdx.x;
    int wave = tid >> 6, lane = tid & 63;
    int mg = lane >> 3;           // 0..7  (4 m each)
    int dg = lane & 7;            // 0..7  (4 d each)
    size_t base = ((size_t)n * 4096 + sp * 128) * 256 + h * 32;

#pragma unroll
    for (int p = 0; p < 2; ++p) {
        int r = p * 64 + (tid >> 2);
        int c = (tid & 3) * 8;
        bf16x8 k8 = *(const bf16x8*)(Kb + base + (size_t)r * 256 + c);
        bf16x8 v8 = *(const bf16x8*)(Vb + base + (size_t)r * 256 + c);
#pragma unroll
        for (int u = 0; u < 8; ++u) { Ks[r][c + u] = (float)k8[u]; Vs[r][c + u] = (float)v8[u]; }
    }
    __syncthreads();

    float acc[4][4] = {};
    float ks4[4] = {};
    int s0 = wave * 32;
    for (int s = s0; s < s0 + 32; ++s) {
        float4 kq = *(float4*)&Ks[s][dg * 4];
        float4 vq = *(float4*)&Vs[s][mg * 4];
        ks4[0] += kq.x; ks4[1] += kq.y; ks4[2] += kq.z; ks4[3] += kq.w;
        acc[0][0] += vq.x * kq.x; acc[0][1] += vq.x * kq.y; acc[0][2] += vq.x * kq.z; acc[0][3] += vq.x * kq.w;
        acc[1][0] += vq.y * kq.x; acc[1][1] += vq.y * kq.y; acc[1][2] += vq.y * kq.z; acc[1][3] += vq.y * kq.w;
        acc[2][0] += vq.z * kq.x; acc[2][1] += vq.z * kq.y; acc[2][2] += vq.z * kq.z; acc[2][3] += vq.z * kq.w;
        acc[3][0] += vq.w * kq.x; acc[3][1] += vq.w * kq.y; acc[3][2] += vq.w * kq.z; acc[3][3] += vq.w * kq.w;
    }
    __syncthreads();

    float* R  = &Ks[0][0];
    float* RS = &Vs[0][0];
#pragma unroll
    for (int mi = 0; mi < 4; ++mi)
#pragma unroll
        for (int dj = 0; dj < 4; ++dj)
            R[wave * 1024 + (mg * 4 + mi) * 32 + dg * 4 + dj] = acc[mi][dj];
    if (mg == 0)
#pragma unroll
        for (int dj = 0; dj < 4; ++dj) RS[wave * 32 + dg * 4 + dj] = ks4[dj];
    __syncthreads();

    int e = tid * 4;
    float4 o0 = *(float4*)&R[e];
    float4 o1 = *(float4*)&R[1024 + e];
    float4 o2 = *(float4*)&R[2048 + e];
    float4 o3 = *(float4*)&R[3072 + e];
    float4 o = make_float4(o0.x + o1.x + o2.x + o3.x, o0.y + o1.y + o2.y + o3.y,
                           o0.z + o1.z + o2.z + o3.z, o0.w + o1.w + o2.w + o3.w);
    *(float4*)&Pkv[((size_t)nh * 32 + sp) * 1024 + e] = o;
    if (tid < 32)
        Pks[((size_t)nh * 32 + sp) * 32 + tid] = RS[tid] + RS[32 + tid] + RS[64 + tid] + RS[96 + tid];
}

// grid (64 nh, 4 quarters), 64 threads (1 wave).
__global__ __launch_bounds__(64) void kv_reduce(const float* __restrict__ Pkv,
                                                const float* __restrict__ Pks,
                                                float* __restrict__ KV,
                                                float* __restrict__ Ksum) {
    int nh = blockIdx.x;
    int q = blockIdx.y;
    int e = (q * 64 + threadIdx.x) * 4;
    float4 s = make_float4(0.f, 0.f, 0.f, 0.f);
    for (int sp = 0; sp < 32; ++sp) {
        float4 p = *(const float4*)&Pkv[((size_t)nh * 32 + sp) * 1024 + e];
        s.x += p.x; s.y += p.y; s.z += p.z; s.w += p.w;
    }
    *(float4*)&KV[(size_t)nh * 1024 + e] = s;
    if (q == 0 && threadIdx.x < 32) {
        float ss = 0.f;
        for (int sp = 0; sp < 32; ++sp) ss += Pks[((size_t)nh * 32 + sp) * 32 + threadIdx.x];
        Ksum[nh * 32 + threadIdx.x] = ss;
    }
}

// ---------------------------------------------------------------------------
// Store: Xb[b,t,c] bf16 -> out[b,c,t] f32
// ---------------------------------------------------------------------------
__global__ __launch_bounds__(1024) void store_kernel(const bf16* __restrict__ Xb,
                                                     float* __restrict__ out) {
    __shared__ float tile[32][33];
    int b = blockIdx.z;
    int t0 = blockIdx.x * 32, c0 = blockIdx.y * 32;
    tile[threadIdx.y][threadIdx.x] =
        (float)Xb[((size_t)b * 4096 + t0 + threadIdx.y) * 256 + c0 + threadIdx.x];
    __syncthreads();
    out[((size_t)b * 256 + c0 + threadIdx.y) * 4096 + t0 + threadIdx.x] =
        tile[threadIdx.x][threadIdx.y];
}

// ---------------------------------------------------------------------------
extern "C" void kernel_launch(void* const* d_in, const int* in_sizes, int n_in,
                              void* d_out, int out_size, void* d_ws, size_t ws_size,
                              hipStream_t stream) {
    const float* ref  = (const float*)d_in[0];
    const float* srcf = (const float*)d_in[1];
    const float* Wq = (const float*)d_in[2];
    const float* bq = (const float*)d_in[3];
    const float* Wk = (const float*)d_in[4];
    const float* bk = (const float*)d_in[5];
    const float* Wv = (const float*)d_in[6];
    const float* bv = (const float*)d_in[7];
    const float* Wo = (const float*)d_in[8];
    const float* bo = (const float*)d_in[9];
    const float* W1 = (const float*)d_in[10];
    const float* b1 = (const float*)d_in[11];
    const float* W2 = (const float*)d_in[12];
    const float* b2 = (const float*)d_in[13];
    const float* g1 = (const float*)d_in[14];
    const float* be1 = (const float*)d_in[15];
    const float* g2 = (const float*)d_in[16];
    const float* be2 = (const float*)d_in[17];

    const size_t SZ = (size_t)8 * 4096 * 256;
    float* ws  = (float*)d_ws;
    float* KVb = ws;                          // 65536 f32
    float* Ksb = KVb + 65536;                 // 2048 f32
    float* Pkv = Ksb + 2048;                  // 2,097,152 f32
    float* Pks = Pkv + 2097152;               // 65536 f32
    bf16*  Wt  = (bf16*)(Pks + 65536);        // 2,097,152 bf16
    bf16*  Xb  = Wt + 2097152;                // SZ bf16 (residual stream)
    bf16*  P2b = Xb + SZ;                     // SZ bf16
    bf16*  Qb  = P2b + SZ;                    // SZ bf16
    // K/V live in d_out (exact 2*SZ bf16 fit); dead before store_kernel runs.
    bf16*  Kb  = (bf16*)d_out;
    bf16*  Vb  = Kb + SZ;
    bf16*  Hb  = Kb;                          // alias: FFN hidden spans Kb+Vb

    wt_conv<<<dim3(16, 16, 24), dim3(32, 32), 0, stream>>>(Wq, Wk, Wv, Wo, W1, W2, Wt);
    encode_kernel<<<dim3(128, 8, 8), dim3(32, 32), 0, stream>>>(ref, srcf, Xb, P2b);

    for (int L = 0; L < 4; ++L) {
        const bf16* WtL = Wt + (size_t)L * 524288;
        const bf16* Akv = (L & 1) ? P2b : Xb;
        gemm_qkv<<<dim3(6, 256), 256, 0, stream>>>(Xb, Akv, WtL,
                                                   bq + L * 256, bk + L * 256, bv + L * 256,
                                                   Qb, Kb, Vb);
        kv_prep_part<<<dim3(32, 64), 256, 0, stream>>>(Kb, Vb, Pkv, Pks);
        kv_reduce<<<dim3(64, 4), 64, 0, stream>>>(Pkv, Pks, KVb, Ksb);
        // attention + O-proj + residual + LN1 fused
        attn_oln<<<256, 512, 0, stream>>>(Qb, KVb, Ksb, WtL + 196608, bo + L * 256,
                                          Xb, g1 + L * 256, be1 + L * 256);
        // FFN1 (relu) -> Hb
        gemm_mfma<1><<<dim3(4, 256), 256, 0, stream>>>(Xb, WtL + 262144, b1 + L * 512, Hb, 512, 256);
        // FFN2 + residual + LN2 fused
        gemm_ln<<<256, 512, 0, stream>>>(Hb, WtL + 393216, b2 + L * 256, Xb,
                                         g2 + L * 256, be2 + L * 256, 512);
    }

    store_kernel<<<dim3(128, 8, 8), dim3(32, 32), 0, stream>>>(Xb, (float*)d_out);
}